// Round 1
// baseline (1508.258 us; speedup 1.0000x reference)
//
#include <hip/hip_runtime.h>
#include <hip/hip_bf16.h>
#include <math.h>

#define LRELU_SLOPE 0.2f
typedef __hip_bfloat16 bf16;
typedef __hip_bfloat162 bf16x2;

typedef short s8v __attribute__((ext_vector_type(8)));   // 8 bf16 (4 VGPRs)
typedef short s4v __attribute__((ext_vector_type(4)));   // 4 bf16 (2 VGPRs)
typedef float f4v __attribute__((ext_vector_type(4)));   // MFMA acc

__device__ __forceinline__ float lrelu(float v) { return v > 0.f ? v : LRELU_SLOPE * v; }
__device__ __forceinline__ float b2f(short b) {
  return __uint_as_float(((unsigned)(unsigned short)b) << 16);
}

__device__ __forceinline__ void st2(float* p, float x, float y) {
  *(float2*)p = float2{x, y};
}

// nontemporal 16B store: streaming output shouldn't evict the h gather set
template <typename T>
__device__ __forceinline__ void nt_store16(void* p, T v) {
  union { T t; unsigned long long q[2]; } u;
  u.t = v;
  __builtin_nontemporal_store(u.q[0], (unsigned long long*)p);
  __builtin_nontemporal_store(u.q[1], (unsigned long long*)p + 1);
}

// ---------------- zero helper (avoid hipMemsetAsync in capture) ----------------

__global__ void k_zero(unsigned int* __restrict__ p, long n) {
  long i = (long)blockIdx.x * blockDim.x + threadIdx.x;
  if (i < n) p[i] = 0u;
}

__global__ void k_zero_out(float* __restrict__ out, int n) {
  int i = blockIdx.x * blockDim.x + threadIdx.x;
  if (i < n) out[i] = 0.f;
}

// ---------------- dtype prep: x -> bf16, W -> bf16 transposed ----------------

__global__ void k_cvt(const float* __restrict__ x, bf16* __restrict__ xb, long n) {
  long i = (long)blockIdx.x * blockDim.x + threadIdx.x;
  if (i < n) xb[i] = __float2bfloat16(x[i]);
}

// W[K][NN] (f32) -> Wt[NN][K] (bf16)
__global__ void k_tw(const float* __restrict__ W, bf16* __restrict__ Wt, int K, int NN) {
  int i = blockIdx.x * blockDim.x + threadIdx.x;
  if (i >= K * NN) return;
  int k = i / NN, n = i - k * NN;
  Wt[(size_t)n * K + k] = __float2bfloat16(W[i]);
}

// ---------------- preprocessing: counting-sort edges by dst ----------------

__global__ void k_hist(const int* __restrict__ dst, int* __restrict__ deg, int E, int Et) {
  int e = blockIdx.x * blockDim.x + threadIdx.x;
  if (e >= Et) return;
  int d = (e < E) ? dst[e] : (e - E);   // self-loops appended
  atomicAdd(&deg[d], 1);
}

__global__ void k_hist1(const int* __restrict__ idx, int* __restrict__ deg, int n) {
  int i = blockIdx.x * blockDim.x + threadIdx.x;
  if (i < n) atomicAdd(&deg[idx[i]], 1);
}

__global__ void k_scan1(const int* __restrict__ deg, int* __restrict__ offs,
                        int* __restrict__ bsum, int n) {
  __shared__ int sd[256];
  int t = threadIdx.x;
  int base = blockIdx.x * 1024 + t * 4;
  int v[4]; int tsum = 0;
#pragma unroll
  for (int i = 0; i < 4; ++i) { v[i] = (base + i < n) ? deg[base + i] : 0; tsum += v[i]; }
  sd[t] = tsum;
  __syncthreads();
  for (int off = 1; off < 256; off <<= 1) {
    int x = (t >= off) ? sd[t - off] : 0;
    __syncthreads();
    sd[t] += x;
    __syncthreads();
  }
  int excl = sd[t] - tsum;
#pragma unroll
  for (int i = 0; i < 4; ++i) { if (base + i < n) offs[base + i] = excl; excl += v[i]; }
  if (t == 255) bsum[blockIdx.x] = sd[255];
}

__global__ void k_scan2(int* bsum, int nb) {
  if (threadIdx.x == 0 && blockIdx.x == 0) {
    int run = 0;
    for (int i = 0; i < nb; ++i) { int t = bsum[i]; bsum[i] = run; run += t; }
  }
}

__global__ void k_scan3(int* __restrict__ offs, const int* __restrict__ bsum, int n, int total) {
  int t = threadIdx.x;
  int base = blockIdx.x * 1024 + t * 4;
  int add = bsum[blockIdx.x];
#pragma unroll
  for (int i = 0; i < 4; ++i) if (base + i < n) offs[base + i] += add;
  if (blockIdx.x == 0 && t == 0) offs[n] = total;
}

__global__ void k_scatter(const int* __restrict__ src, const int* __restrict__ dst,
                          const int* __restrict__ offs, int* __restrict__ cur,
                          int* __restrict__ ssrc, int E, int Et) {
  int e = blockIdx.x * blockDim.x + threadIdx.x;
  if (e >= Et) return;
  int s, d;
  if (e < E) { s = src[e]; d = dst[e]; } else { s = d = e - E; }
  int pos = offs[d] + atomicAdd(&cur[d], 1);
  ssrc[pos] = s;
}

// ---------------- bf16 MFMA GEMM: C[M,NN](bf16) = A[M,K](bf16) @ Wt[NN,K](bf16)^T ----

__global__ __launch_bounds__(256) void k_gemm_mfma(const bf16* __restrict__ A,
                                                   const bf16* __restrict__ Wt,
                                                   bf16* __restrict__ C,
                                                   int K, int NN) {
  __shared__ __align__(16) short sA[64 * 64];   // 8 KB, 64 rows x 64 cols bf16
  int t = threadIdx.x;
  int wv = t >> 6, lane = t & 63;
  int quad = lane >> 4, l15 = lane & 15;
  size_t bm0 = (size_t)blockIdx.x * 64;
  int bn0 = blockIdx.y * 64;
  const bf16* Ab = A + bm0 * K;
  const bf16* Bp = Wt + (size_t)(bn0 + wv * 16 + l15) * K;  // this lane's weight row
  f4v acc[4] = {f4v{0,0,0,0}, f4v{0,0,0,0}, f4v{0,0,0,0}, f4v{0,0,0,0}};

  for (int kb = 0; kb < K; kb += 64) {
#pragma unroll
    for (int j = 0; j < 2; ++j) {
      int idx = j * 256 + t;
      int row = idx >> 3, p = idx & 7;
      int c = p ^ (row & 7);                  // global 16B-chunk landing at pos p
      const bf16* g = Ab + (size_t)row * K + kb + c * 8;
      __builtin_amdgcn_global_load_lds(
          (const __attribute__((address_space(1))) void*)g,
          (__attribute__((address_space(3))) void*)((char*)sA + (size_t)(j * 256 + wv * 64) * 16),
          16, 0, 0);
    }
    __syncthreads();
#pragma unroll
    for (int kk = 0; kk < 2; ++kk) {
      s8v bfrag = *(const s8v*)(Bp + kb + kk * 32 + quad * 8);
#pragma unroll
      for (int ms = 0; ms < 4; ++ms) {
        int row = ms * 16 + l15;
        int pos = (kk * 4 + quad) ^ (row & 7);
        s8v afrag = *(const s8v*)((const char*)sA + (size_t)row * 128 + pos * 16);
        acc[ms] = __builtin_amdgcn_mfma_f32_16x16x32_bf16(afrag, bfrag, acc[ms], 0, 0, 0);
      }
    }
    __syncthreads();
  }
  // C/D layout: col = lane&15, row = quad*4 + reg  [m89/m91 verified]
  int coln = bn0 + wv * 16 + l15;
#pragma unroll
  for (int ms = 0; ms < 4; ++ms)
#pragma unroll
    for (int r = 0; r < 4; ++r)
      C[(bm0 + ms * 16 + quad * 4 + r) * NN + coln] = __float2bfloat16(acc[ms][r]);
}

// ---------------- attention logits: one wave per node, 16 lanes per head ----------------
// al_s/al_d stored PADDED to 4 floats per node (H=3) so the per-edge gather in
// k_attn_agg is a single dwordx4 instead of 3 scalar dword gathers.

template <int H>
__global__ void k_al(const bf16* __restrict__ h, const float* __restrict__ as,
                     const float* __restrict__ ad, float* __restrict__ al_s,
                     float* __restrict__ al_d, int N) {
  constexpr int SP = (H > 1) ? 4 : 1;
  int n = (blockIdx.x * blockDim.x + threadIdx.x) >> 6;
  int lane = threadIdx.x & 63;
  if (n >= N) return;
  int hd = lane >> 4;
  bool active = (hd < H);
  int hdc = active ? hd : 0;
  int f8 = (lane & 15) * 8;
  const bf16* hp = h + (size_t)n * (H * 128) + hdc * 128 + f8;
  s8v hv = *(const s8v*)hp;
  float ss = 0.f, sd = 0.f;
#pragma unroll
  for (int i = 0; i < 8; ++i) {
    float v = b2f(hv[i]);
    ss += v * as[hdc * 128 + f8 + i];
    sd += v * ad[hdc * 128 + f8 + i];
  }
#pragma unroll
  for (int off = 8; off; off >>= 1) {
    ss += __shfl_xor(ss, off, 64);
    sd += __shfl_xor(sd, off, 64);
  }
  if (active && (lane & 15) == 0) {
    al_s[n * SP + hd] = ss;
    al_d[n * SP + hd] = sd;
  }
}

// -------- fused segment-softmax + weighted aggregation: one wave per node --------
// Single pass over edges (online softmax): per 64-edge chunk, gather e values
// (one dwordx4 from padded al_s), wave-reduce the chunk max, exp, stash
// {src, ex[H]} in LDS; then a serial 8-deep loop reads edge records via
// broadcast ds_read while 8 x dwordx4 h-row gathers are in flight. Each active
// lane owns CPL contiguous channels of exactly one head (48 lanes x 16B for
// H=3, 32 lanes x 8B for H=1), so the h gather is ONE wide load per edge-slot
// and den is one add per slot. Rescale branch keeps deg>64 exact (never taken
// here: Poisson(8)+1, max deg ~31).

template <int CPL> struct HVec;
template <> struct HVec<8> { typedef s8v T; };
template <> struct HVec<4> { typedef s4v T; };

template <int H, typename OT>
__global__ __launch_bounds__(256) void k_attn_agg(const bf16* __restrict__ hbuf,
                           const int* __restrict__ ssrc,
                           const int* __restrict__ offs, const float* __restrict__ al_s,
                           const float* __restrict__ al_d, const float* __restrict__ bias,
                           OT* __restrict__ out, int N) {
  constexpr int SW  = (H > 1) ? 4 : 2;   // stash record (floats)
  constexpr int ROW = H * 128;           // channels per node row
  constexpr int CPL = (H > 1) ? 8 : 4;   // channels per active lane
  constexpr int NL  = ROW / CPL;         // active lanes (48 or 32)
  typedef typename HVec<CPL>::T hvec;

  __shared__ __align__(16) float stash[4][64 * SW];
  int n = (blockIdx.x * blockDim.x + threadIdx.x) >> 6;
  int lane = threadIdx.x & 63;
  if (n >= N) return;
  float* st = stash[threadIdx.x >> 6];
  int start = offs[n], end = offs[n + 1];

  float ald[H];
  if constexpr (H > 1) {
    float4 t = *(const float4*)&al_d[(size_t)n * 4];
    ald[0] = t.x; ald[1] = t.y; ald[2] = t.z;
  } else {
    ald[0] = al_d[n];
  }

  bool act = lane < NL;
  int c0 = act ? lane * CPL : 0;
  int hd_l = c0 >> 7;                    // this lane's head (0 for idle lanes)

  float m[H];
  float den = 0.f;                       // own-head denominator
  float acc[CPL];
#pragma unroll
  for (int hd = 0; hd < H; ++hd) m[hd] = -1e30f;
#pragma unroll
  for (int i = 0; i < CPL; ++i) acc[i] = 0.f;

  for (int cb = start; cb < end; cb += 64) {
    int cl = end - cb; if (cl > 64) cl = 64;
    bool el = lane < cl;
    int mys = el ? ssrc[cb + lane] : 0;
    float ev[H];
    if constexpr (H > 1) {
      float4 av = *(const float4*)&al_s[(size_t)mys * 4];
      ev[0] = av.x; ev[1] = av.y; ev[2] = av.z;
    } else {
      ev[0] = al_s[mys];
    }
#pragma unroll
    for (int hd = 0; hd < H; ++hd)
      ev[hd] = el ? lrelu(ev[hd] + ald[hd]) : -1e30f;

    // chunk max (fused -- no separate max pass over the edges)
    float nm[H];
#pragma unroll
    for (int hd = 0; hd < H; ++hd) {
      float v = ev[hd];
#pragma unroll
      for (int off = 32; off; off >>= 1) v = fmaxf(v, __shfl_xor(v, off, 64));
      nm[hd] = fmaxf(v, m[hd]);
    }
    if (cb > start) {                    // online rescale; wave-uniform branch
      float sc[H];
#pragma unroll
      for (int hd = 0; hd < H; ++hd) sc[hd] = __expf(m[hd] - nm[hd]);
      float so = sc[hd_l];
      den *= so;
#pragma unroll
      for (int i = 0; i < CPL; ++i) acc[i] *= so;
    }
#pragma unroll
    for (int hd = 0; hd < H; ++hd) m[hd] = nm[hd];

    float myex[H];
#pragma unroll
    for (int hd = 0; hd < H; ++hd) myex[hd] = el ? __expf(ev[hd] - m[hd]) : 0.f;

    // stash this chunk's edge records (wave-private region; wave-synchronous)
    __builtin_amdgcn_wave_barrier();
    if constexpr (H > 1) {
      float4 s4{__int_as_float(mys), myex[0], myex[1], myex[2]};
      *(float4*)&st[lane * 4] = s4;
    } else {
      float2 s2{__int_as_float(mys), myex[0]};
      *(float2*)&st[lane * 2] = s2;
    }
    asm volatile("s_waitcnt lgkmcnt(0)" ::: "memory");
    __builtin_amdgcn_wave_barrier();

    for (int r = 0; r < cl; r += 8) {
      int su[8]; float a[8];
#pragma unroll
      for (int u = 0; u < 8; ++u) {
        if constexpr (H > 1) {
          float4 ed = *(const float4*)&st[(r + u) * 4];   // broadcast ds_read_b128
          su[u] = __float_as_int(ed.x);
          a[u] = (hd_l == 0) ? ed.y : ((hd_l == 1) ? ed.z : ed.w);
        } else {
          float2 ed = *(const float2*)&st[(r + u) * 2];
          su[u] = __float_as_int(ed.x);
          a[u] = ed.y;
        }
        den += a[u];                     // tail slots stash a==0
      }
      hvec hv[8];
#pragma unroll
      for (int u = 0; u < 8; ++u)
        hv[u] = *(const hvec*)(hbuf + (size_t)su[u] * ROW + c0);
#pragma unroll
      for (int u = 0; u < 8; ++u)
#pragma unroll
        for (int i = 0; i < CPL; ++i)
          acc[i] += a[u] * b2f(hv[u][i]);
    }
  }

  if (act) {
    float rr = 1.f / (den + 1e-16f);
    OT* op = out + (size_t)n * ROW + c0;
    if constexpr (sizeof(OT) == 2) {
      s8v ov;
#pragma unroll
      for (int i = 0; i < CPL; ++i) {
        float o = lrelu(acc[i] * rr + bias[c0 + i]);
        bf16 b = __float2bfloat16(o);
        ov[i] = *(short*)&b;
      }
      nt_store16(op, ov);
    } else {
      float4 ov;
      ov.x = lrelu(acc[0] * rr + bias[c0 + 0]);
      ov.y = lrelu(acc[1] * rr + bias[c0 + 1]);
      ov.z = lrelu(acc[2] * rr + bias[c0 + 2]);
      ov.w = lrelu(acc[3] * rr + bias[c0 + 3]);
      nt_store16(op, ov);
    }
  }
}

// ---------------- global mean pool: one wave per graph, no atomics ----------------

__global__ void k_pool(const float* __restrict__ h, const int* __restrict__ goffs,
                       float* __restrict__ out, int G) {
  int g = (blockIdx.x * blockDim.x + threadIdx.x) >> 6;
  int lane = threadIdx.x & 63;
  if (g >= G) return;
  int s = goffs[g], e = goffs[g + 1];
  float ax = 0.f, ay = 0.f;
  for (int n = s; n < e; ++n) {
    float2 v = *(const float2*)&h[(size_t)n * 128 + lane * 2];
    ax += v.x; ay += v.y;
  }
  float c = fmaxf((float)(e - s), 1.f);
  st2(&out[(size_t)g * 128 + lane * 2], ax / c, ay / c);
}

// ---------------- host launcher ----------------

extern "C" void kernel_launch(void* const* d_in, const int* in_sizes, int n_in,
                              void* d_out, int out_size, void* d_ws, size_t ws_size,
                              hipStream_t stream) {
  const float* x   = (const float*)d_in[0];
  const int*   ei  = (const int*)d_in[1];
  const int*   bat = (const int*)d_in[2];
  const float* W1  = (const float*)d_in[3];
  const float* a1s = (const float*)d_in[4];
  const float* a1d = (const float*)d_in[5];
  const float* b1  = (const float*)d_in[6];
  const float* W2  = (const float*)d_in[7];
  const float* a2s = (const float*)d_in[8];
  const float* a2d = (const float*)d_in[9];
  const float* b2  = (const float*)d_in[10];
  const float* W3  = (const float*)d_in[11];
  const float* a3s = (const float*)d_in[12];
  const float* a3d = (const float*)d_in[13];
  const float* b3  = (const float*)d_in[14];
  float* out = (float*)d_out;

  const int N = in_sizes[2];          // 200000
  const int E = in_sizes[1] / 2;      // 1600000
  const int Et = E + N;               // with self-loops
  const int G = out_size / 128;       // 5000

  // ---- workspace carve (bf16 intermediates) ----
  char* p = (char*)d_ws;
  auto carve = [&](size_t bytes) { void* r = (void*)p; p += (bytes + 255) & ~(size_t)255; return r; };
  bf16*  bufA   = (bf16*)carve((size_t)N * 384 * 2);   // agg out / GEMM A; also hosts xb & fp32 layer-3 out
  bf16*  bufB   = (bf16*)carve((size_t)N * 384 * 2);   // GEMM output h
  float* al_s   = (float*)carve((size_t)N * 4 * 4);    // padded to 4 floats/node
  float* al_d   = (float*)carve((size_t)N * 4 * 4);
  int*   ssrc   = (int*)carve((size_t)Et * 4);
  int*   offs   = (int*)carve((size_t)(N + 1) * 4);
  int*   deg    = (int*)carve((size_t)N * 4);
  int*   cur    = (int*)carve((size_t)N * 4);
  int*   bsum   = (int*)carve(4096 * 4);
  int*   gdeg   = (int*)carve((size_t)G * 4);
  int*   goffs  = (int*)carve((size_t)(G + 1) * 4);
  bf16*  Wt1    = (bf16*)carve((size_t)384 * 128 * 2);
  bf16*  Wt2    = (bf16*)carve((size_t)384 * 384 * 2);
  bf16*  Wt3    = (bf16*)carve((size_t)128 * 384 * 2);
  size_t need = (size_t)(p - (char*)d_ws);

  if (ws_size < need) {
    k_zero_out<<<(out_size + 255) / 256, 256, 0, stream>>>(out, out_size);
    return;
  }

  const int* esrc = ei;
  const int* edst = ei + E;

  int ebl = (Et + 255) / 256;
  int NB = (N + 1023) / 1024;
  int GB = (G + 1023) / 1024;
  int nodeWaveBlocks = (N * 64 + 255) / 256;

  // ---- prep: weight transpose+cast, x cast (xb aliases bufA) ----
  bf16* xb = bufA;
  k_cvt<<<((long)N * 128 + 255) / 256, 256, 0, stream>>>(x, xb, (long)N * 128);
  k_tw<<<(128 * 384 + 255) / 256, 256, 0, stream>>>(W1, Wt1, 128, 384);
  k_tw<<<(384 * 384 + 255) / 256, 256, 0, stream>>>(W2, Wt2, 384, 384);
  k_tw<<<(384 * 128 + 255) / 256, 256, 0, stream>>>(W3, Wt3, 384, 128);

  // ---- sort edges by dst ----
  k_zero<<<(N + 255) / 256, 256, 0, stream>>>((unsigned int*)deg, N);
  k_hist<<<ebl, 256, 0, stream>>>(edst, deg, E, Et);
  k_scan1<<<NB, 256, 0, stream>>>(deg, offs, bsum, N);
  k_scan2<<<1, 64, 0, stream>>>(bsum, NB);
  k_scan3<<<NB, 256, 0, stream>>>(offs, bsum, N, Et);
  k_zero<<<(N + 255) / 256, 256, 0, stream>>>((unsigned int*)cur, N);
  k_scatter<<<ebl, 256, 0, stream>>>(esrc, edst, offs, cur, ssrc, E, Et);

  // ---- graph offsets for pool (batch is sorted) ----
  k_zero<<<(G + 255) / 256, 256, 0, stream>>>((unsigned int*)gdeg, G);
  k_hist1<<<(N + 255) / 256, 256, 0, stream>>>(bat, gdeg, N);
  k_scan1<<<GB, 256, 0, stream>>>(gdeg, goffs, bsum, G);
  k_scan2<<<1, 64, 0, stream>>>(bsum, GB);
  k_scan3<<<GB, 256, 0, stream>>>(goffs, bsum, G, N);

  dim3 g1(N / 64, 6), g2(N / 64, 6), g3(N / 64, 2);

  // ---- layer 1: xb[N,128] @ W1 -> bufB[N,384] ----
  k_gemm_mfma<<<g1, 256, 0, stream>>>(xb, Wt1, bufB, 128, 384);
  k_al<3><<<nodeWaveBlocks, 256, 0, stream>>>(bufB, a1s, a1d, al_s, al_d, N);
  k_attn_agg<3, bf16><<<nodeWaveBlocks, 256, 0, stream>>>(bufB, ssrc, offs, al_s, al_d, b1, bufA, N);

  // ---- layer 2: bufA[N,384] @ W2 -> bufB[N,384] ----
  k_gemm_mfma<<<g2, 256, 0, stream>>>(bufA, Wt2, bufB, 384, 384);
  k_al<3><<<nodeWaveBlocks, 256, 0, stream>>>(bufB, a2s, a2d, al_s, al_d, N);
  k_attn_agg<3, bf16><<<nodeWaveBlocks, 256, 0, stream>>>(bufB, ssrc, offs, al_s, al_d, b2, bufA, N);

  // ---- layer 3: bufA[N,384] @ W3 -> bufB[N,128], heads=1, fp32 agg out ----
  k_gemm_mfma<<<g3, 256, 0, stream>>>(bufA, Wt3, bufB, 384, 128);
  k_al<1><<<nodeWaveBlocks, 256, 0, stream>>>(bufB, a3s, a3d, al_s, al_d, N);
  float* out3 = (float*)bufA;
  k_attn_agg<1, float><<<nodeWaveBlocks, 256, 0, stream>>>(bufB, ssrc, offs, al_s, al_d, b3, out3, N);

  // ---- global mean pool: segmented, atomic-free ----
  k_pool<<<(G * 64 + 255) / 256, 256, 0, stream>>>(out3, goffs, out, G);
}